// Round 1
// baseline (187.986 us; speedup 1.0000x reference)
//
#include <hip/hip_runtime.h>
#include <math.h>

// Problem constants (from reference)
constexpr int B = 8;
constexpr int S = 4096;
constexpr int H = 1024;
constexpr int N_SPANS = 100;
constexpr int MAX_LEN = 64;

// One block per (b, span). 256 threads; thread t owns channels [4t, 4t+4)
// as a float4 -> each position is one coalesced 4KB row read.
__global__ __launch_bounds__(256)
void maxpool_spans_kernel(const float* __restrict__ ctx,
                          const int* __restrict__ spans_begin,
                          const int* __restrict__ spans_len,
                          float* __restrict__ out)
{
    const int span = blockIdx.x;              // 0 .. B*N_SPANS-1
    const int b    = span / N_SPANS;

    int bg = spans_begin[span];
    // defensive clamp (reference clips gather indices to [0, S-1])
    if (bg < 0) bg = 0;
    if (bg > S - MAX_LEN) bg = S - MAX_LEN;

    int ln = spans_len[span];
    if (ln < 1) ln = 1;                       // eff_len = max(len, 1)
    if (ln > MAX_LEN) ln = MAX_LEN;

    const float4* __restrict__ row =
        (const float4*)(ctx) + ((size_t)b * S + (size_t)bg) * (H / 4) + threadIdx.x;
    const int stride = H / 4;                 // float4 elements per row

    float4 acc;
    acc.x = -INFINITY; acc.y = -INFINITY; acc.z = -INFINITY; acc.w = -INFINITY;

    #pragma unroll 4
    for (int p = 0; p < ln; ++p) {
        float4 v = row[(size_t)p * stride];
        acc.x = fmaxf(acc.x, v.x);
        acc.y = fmaxf(acc.y, v.y);
        acc.z = fmaxf(acc.z, v.z);
        acc.w = fmaxf(acc.w, v.w);
    }

    float4* __restrict__ o = (float4*)(out) + (size_t)span * (H / 4) + threadIdx.x;
    *o = acc;
}

extern "C" void kernel_launch(void* const* d_in, const int* in_sizes, int n_in,
                              void* d_out, int out_size, void* d_ws, size_t ws_size,
                              hipStream_t stream)
{
    const float* ctx        = (const float*)d_in[0];
    const int*   spans_begin = (const int*)d_in[1];
    const int*   spans_len   = (const int*)d_in[2];
    float*       out         = (float*)d_out;

    dim3 grid(B * N_SPANS);
    dim3 block(256);
    maxpool_spans_kernel<<<grid, block, 0, stream>>>(ctx, spans_begin, spans_len, out);
}

// Round 2
// 183.777 us; speedup vs baseline: 1.0229x; 1.0229x over previous
//
#include <hip/hip_runtime.h>
#include <math.h>

// Problem constants (from reference)
constexpr int B = 8;
constexpr int S = 4096;
constexpr int H = 1024;
constexpr int N_SPANS = 100;
constexpr int MAX_LEN = 64;
constexpr int F4_PER_ROW = H / 4;      // 256 float4 per row
constexpr int QUARTER_F4 = 64;         // 64 float4 (=256 channels) per block

// Grid: (B*N_SPANS, 4). blockIdx.y = channel quarter (256 channels).
// Block: 256 threads = 4 waves. Wave w handles positions p = w, w+4, ...
// (max 16 serial loads per wave instead of 64) -> 4x memory-level
// parallelism vs one-block-per-span. 4-way wave combine via LDS.
__global__ __launch_bounds__(256)
void maxpool_spans_kernel(const float* __restrict__ ctx,
                          const int* __restrict__ spans_begin,
                          const int* __restrict__ spans_len,
                          float* __restrict__ out)
{
    const int span    = blockIdx.x;           // 0 .. B*N_SPANS-1
    const int quarter = blockIdx.y;           // 0 .. 3
    const int b       = span / N_SPANS;
    const int wave    = threadIdx.x >> 6;     // 0 .. 3 (position slice)
    const int lane    = threadIdx.x & 63;     // float4 lane within quarter

    int bg = spans_begin[span];
    if (bg < 0) bg = 0;
    if (bg > S - MAX_LEN) bg = S - MAX_LEN;   // ref clips idx to [0, S-1]

    int ln = spans_len[span];
    if (ln < 1) ln = 1;                       // eff_len = max(len, 1)
    if (ln > MAX_LEN) ln = MAX_LEN;

    const int f4 = quarter * QUARTER_F4 + lane;   // 0..255
    const float4* __restrict__ base =
        (const float4*)(ctx) + ((size_t)b * S + (size_t)bg) * F4_PER_ROW + f4;

    float4 acc;
    acc.x = -INFINITY; acc.y = -INFINITY; acc.z = -INFINITY; acc.w = -INFINITY;

    // wave 0 always has >=1 position (ln >= 1); other waves may contribute
    // -INF, which is the identity for max.
    #pragma unroll 4
    for (int p = wave; p < ln; p += 4) {
        float4 v = base[(size_t)p * F4_PER_ROW];
        acc.x = fmaxf(acc.x, v.x);
        acc.y = fmaxf(acc.y, v.y);
        acc.z = fmaxf(acc.z, v.z);
        acc.w = fmaxf(acc.w, v.w);
    }

    __shared__ float4 red[256];               // 4 KB
    red[threadIdx.x] = acc;
    __syncthreads();

    if (wave == 0) {
        float4 a = red[lane];
        float4 b1 = red[64 + lane];
        float4 c = red[128 + lane];
        float4 d = red[192 + lane];
        a.x = fmaxf(fmaxf(a.x, b1.x), fmaxf(c.x, d.x));
        a.y = fmaxf(fmaxf(a.y, b1.y), fmaxf(c.y, d.y));
        a.z = fmaxf(fmaxf(a.z, b1.z), fmaxf(c.z, d.z));
        a.w = fmaxf(fmaxf(a.w, b1.w), fmaxf(c.w, d.w));
        float4* __restrict__ o = (float4*)(out) + (size_t)span * F4_PER_ROW + f4;
        *o = a;
    }
}

extern "C" void kernel_launch(void* const* d_in, const int* in_sizes, int n_in,
                              void* d_out, int out_size, void* d_ws, size_t ws_size,
                              hipStream_t stream)
{
    const float* ctx         = (const float*)d_in[0];
    const int*   spans_begin = (const int*)d_in[1];
    const int*   spans_len   = (const int*)d_in[2];
    float*       out         = (float*)d_out;

    dim3 grid(B * N_SPANS, 4);
    dim3 block(256);
    maxpool_spans_kernel<<<grid, block, 0, stream>>>(ctx, spans_begin, spans_len, out);
}

// Round 3
// 183.298 us; speedup vs baseline: 1.0256x; 1.0026x over previous
//
#include <hip/hip_runtime.h>
#include <math.h>

// Problem constants (from reference)
constexpr int B = 8;
constexpr int S = 4096;
constexpr int H = 1024;
constexpr int N_SPANS = 100;
constexpr int MAX_LEN = 64;
constexpr int F4_PER_ROW = H / 4;      // 256 float4 per row
constexpr int QUARTER_F4 = 64;         // 64 float4 (=256 channels) per block

// Grid: (B*N_SPANS, 4). blockIdx.y = channel quarter (256 channels).
// Block: 256 threads = 4 waves. Wave w handles positions p = w + 4j,
// j = 0..15. Loads are issued in two predicated batches of 8 (indices
// clamped to ln-1; invalid lanes masked to -INF after the load) so each
// wave keeps 8 loads in flight per wait group instead of trickling
// load->wait->fmax. Clamped duplicate loads hit L1 (same line), so HBM
// traffic is unchanged. Group-skip test is wave-uniform (scalar branch).
__global__ __launch_bounds__(256)
void maxpool_spans_kernel(const float* __restrict__ ctx,
                          const int* __restrict__ spans_begin,
                          const int* __restrict__ spans_len,
                          float* __restrict__ out)
{
    const int span    = blockIdx.x;           // 0 .. B*N_SPANS-1
    const int quarter = blockIdx.y;           // 0 .. 3
    const int b       = span / N_SPANS;
    const int wave    = threadIdx.x >> 6;     // 0 .. 3 (position slice)
    const int lane    = threadIdx.x & 63;     // float4 lane within quarter

    int bg = spans_begin[span];
    if (bg < 0) bg = 0;
    if (bg > S - MAX_LEN) bg = S - MAX_LEN;   // ref clips idx to [0, S-1]

    int ln = spans_len[span];
    if (ln < 1) ln = 1;                       // eff_len = max(len, 1)
    if (ln > MAX_LEN) ln = MAX_LEN;

    const int f4 = quarter * QUARTER_F4 + lane;   // 0..255
    const float4* __restrict__ base =
        (const float4*)(ctx) + ((size_t)b * S + (size_t)bg) * F4_PER_ROW + f4;

    float4 acc;
    acc.x = -INFINITY; acc.y = -INFINITY; acc.z = -INFINITY; acc.w = -INFINITY;

    const int pmax = ln - 1;                  // clamp target (always valid)

    #pragma unroll
    for (int g = 0; g < 2; ++g) {             // two batches of 8 positions
        const int p0 = wave + 4 * (8 * g);    // first position of batch
        if (p0 >= ln) break;                  // wave-uniform skip

        float4 v[8];
        #pragma unroll
        for (int j = 0; j < 8; ++j) {
            int p  = wave + 4 * (8 * g + j);
            int pc = p < pmax ? p : pmax;     // clamped: always in-bounds
            v[j] = base[(size_t)pc * F4_PER_ROW];
        }
        #pragma unroll
        for (int j = 0; j < 8; ++j) {
            int p = wave + 4 * (8 * g + j);
            if (p < ln) {
                acc.x = fmaxf(acc.x, v[j].x);
                acc.y = fmaxf(acc.y, v[j].y);
                acc.z = fmaxf(acc.z, v[j].z);
                acc.w = fmaxf(acc.w, v[j].w);
            }
        }
    }

    __shared__ float4 red[256];               // 4 KB
    red[threadIdx.x] = acc;
    __syncthreads();

    if (wave == 0) {
        float4 a  = red[lane];
        float4 b1 = red[64 + lane];
        float4 c  = red[128 + lane];
        float4 d  = red[192 + lane];
        a.x = fmaxf(fmaxf(a.x, b1.x), fmaxf(c.x, d.x));
        a.y = fmaxf(fmaxf(a.y, b1.y), fmaxf(c.y, d.y));
        a.z = fmaxf(fmaxf(a.z, b1.z), fmaxf(c.z, d.z));
        a.w = fmaxf(fmaxf(a.w, b1.w), fmaxf(c.w, d.w));
        float4* __restrict__ o = (float4*)(out) + (size_t)span * F4_PER_ROW + f4;
        *o = a;
    }
}

extern "C" void kernel_launch(void* const* d_in, const int* in_sizes, int n_in,
                              void* d_out, int out_size, void* d_ws, size_t ws_size,
                              hipStream_t stream)
{
    const float* ctx         = (const float*)d_in[0];
    const int*   spans_begin = (const int*)d_in[1];
    const int*   spans_len   = (const int*)d_in[2];
    float*       out         = (float*)d_out;

    dim3 grid(B * N_SPANS, 4);
    dim3 block(256);
    maxpool_spans_kernel<<<grid, block, 0, stream>>>(ctx, spans_begin, spans_len, out);
}